// Round 8
// baseline (308.459 us; speedup 1.0000x reference)
//
#include <hip/hip_runtime.h>

#define LQ 384
#define DF 64
#define NWIN 16
#define PERW 15      // NG + NF
#define STEPW 16     // 1 + NG + NF
#define NPAIR 240    // NWIN * PERW
#define NWAVE 6      // row-slabs (producer waves and consumer waves each)
#define PW 32        // panel width (cols per round)
#define NPANEL 12    // 384 / PW
#define NROUND2 18   // NPANEL + NWAVE - 1 + 1 (producer lead)
#define BST 66       // B LDS row stride (floats)
#define DCS 68       // D-tile column stride (col-major [32 cols][68])
#define C2  0.28853900817779268f   // 1/(5*ln2)  (pre-scale: R' = R*C2)
#define L2C 3.4657359027997265f    // 5*ln2      (unscale at extraction)
#define BIGS (1e9f * C2)           // BIG in scaled domain

typedef float v2f __attribute__((ext_vector_type(2)));

__device__ __forceinline__ float fexp2(float x) { return __builtin_amdgcn_exp2f(x); }
__device__ __forceinline__ float flog2(float x) { return __builtin_amdgcn_logf(x); }

// wave_shr:1 -- lane l gets lane l-1's value (VALU pipe). lane0 keeps own (fixed up).
__device__ __forceinline__ float wshr1f(float x) {
  int xi = __float_as_int(x);
  return __int_as_float(__builtin_amdgcn_update_dpp(xi, xi, 0x138, 0xF, 0xF, false));
}

// ---------------------------------------------------------------------------
// Producer-consumer soft-DTW, 2 barriers/round. Waves 0-5: GEMM for panel
// rr-g into REGISTERS during phase 1 (B from LDS, A from global/L1), dump to
// single-buffered Dt in phase 2. Waves 6-11: DP (validated r5/r7 numerics) on
// Dt written last round, during phase 1.
// ---------------------------------------------------------------------------
__global__ __launch_bounds__(768, 3) void sdtw_kernel(const float* __restrict__ data,
                                                      const int* __restrict__ lens,
                                                      float* __restrict__ dist) {
  __shared__ __align__(16) float Bsh[LQ * BST];          // 101376 B
  __shared__ __align__(16) float Dt[NWAVE][32 * DCS];    // 52224 B (D*C2, col-major)
  __shared__ __align__(16) float sqA[LQ];                // 1536 B
  __shared__ __align__(16) float sqB[LQ];                // 1536 B
  __shared__ __align__(16) float bnd[NWAVE][2][36];      // 1728 B  (158400 total)

  const int p_id = blockIdx.x;
  const int wwin = p_id / PERW;
  const int o = p_id - wwin * PERW;
  const int aRow = wwin * STEPW;
  const int bRow = aRow + 1 + o;
  const int la = lens[aRow];
  const int lb = lens[bRow];
  const int tid = threadIdx.x;
  const int w = tid >> 6;        // 0..11
  const int lane = tid & 63;

  const float* __restrict__ A  = data + (size_t)aRow * LQ * DF;
  const float* __restrict__ Bp = data + (size_t)bRow * LQ * DF;

  // ---- stage B into LDS (all 768 threads); sqA (threads 0..383, global) ----
  {
    const float4* B4 = (const float4*)Bp;
    for (int q = tid; q < LQ * 16; q += 768) {
      float4 v = B4[q];
      int row = q >> 4, c4 = (q & 15) << 2;
      float* dst = &Bsh[row * BST + c4];
      ((float2*)dst)[0] = make_float2(v.x, v.y);
      ((float2*)dst)[1] = make_float2(v.z, v.w);
    }
  }
  if (tid < LQ) {
    const float4* A4 = (const float4*)(A + (size_t)tid * DF);
    float s = 0.f;
#pragma unroll
    for (int k = 0; k < 16; ++k) {
      float4 v = A4[k];
      s = fmaf(v.x, v.x, s); s = fmaf(v.y, v.y, s);
      s = fmaf(v.z, v.z, s); s = fmaf(v.w, v.w, s);
    }
    sqA[tid] = s;
  }
  __syncthreads();
  if (tid < LQ) {
    float s = 0.f;
    const float2* row = (const float2*)&Bsh[tid * BST];
#pragma unroll
    for (int k = 0; k < 32; ++k) { float2 v = row[k]; s = fmaf(v.x, v.x, s); s = fmaf(v.y, v.y, s); }
    sqB[tid] = s;
  }
  __syncthreads();

  // extraction target: R[la][lb] at DP wave wt, lane it, panel pt
  const int wt = (la - 1) >> 6;
  const int it = (la - 1) & 63;
  const int pt = (lb - 1) >> 5;
  const int tstar = it + ((lb - 1) & 31);
  const int rstar2 = wt + pt + 1;               // consumer round index
  const float scale = L2C / (float)(la + lb);

  if (w < NWAVE) {
    // =====================  GEMM (producer) waves  =========================
    const int g = w;
    const int rg = lane >> 3, cg = lane & 7;    // 8 rows x 4 cols per lane
    const bool gActive = (64 * g < la);
    const float4* A4g = (const float4*)(A + (size_t)(64 * g + 8 * rg) * DF);
    float sa8[8];
    *(float4*)&sa8[0] = *(const float4*)&sqA[64 * g + 8 * rg];
    *(float4*)&sa8[4] = *(const float4*)&sqA[64 * g + 8 * rg + 4];
    float* DtW = &Dt[g][0];

    for (int rr = 0; rr < NROUND2; ++rr) {
      __syncthreads();                           // S1
      const int p = rr - g;
      const bool doit = ((unsigned)p < (unsigned)NPANEL) && gActive && (32 * p < lb);
      v2f acc[8][4];
      if (doit) {
        // ----- phase 1: GEMM into registers (B from LDS, A from L1) -----
#pragma unroll
        for (int a_ = 0; a_ < 8; ++a_)
#pragma unroll
          for (int b_ = 0; b_ < 4; ++b_) { acc[a_][b_].x = 0.f; acc[a_][b_].y = 0.f; }
        const float* Bb = &Bsh[(PW * p + 4 * cg) * BST];
#pragma unroll
        for (int kk = 0; kk < 16; ++kk) {
          v2f b0[4], b1[4];
#pragma unroll
          for (int cc = 0; cc < 4; ++cc) {
            b0[cc] = *(const v2f*)&Bb[cc * BST + 4 * kk];
            b1[cc] = *(const v2f*)&Bb[cc * BST + 4 * kk + 2];
          }
#pragma unroll
          for (int rrr = 0; rrr < 8; ++rrr) {
            float4 v = A4g[rrr * 16 + kk];
            v2f a0, a1;
            a0.x = v.x; a0.y = v.y; a1.x = v.z; a1.y = v.w;
#pragma unroll
            for (int cc = 0; cc < 4; ++cc) {
              acc[rrr][cc] = __builtin_elementwise_fma(a0, b0[cc], acc[rrr][cc]);
              acc[rrr][cc] = __builtin_elementwise_fma(a1, b1[cc], acc[rrr][cc]);
            }
          }
        }
      }
      __syncthreads();                           // S2 (consumers done reading Dt)
      if (doit) {
        // ----- phase 2: dump D' = (sqA + sqB - 2*dot) * C2 to Dt -----
        float4 sb = *(const float4*)&sqB[PW * p + 4 * cg];
        float sbv[4] = {sb.x, sb.y, sb.z, sb.w};
#pragma unroll
        for (int cc = 0; cc < 4; ++cc) {
          float4 lo, hi;
          lo.x = (sa8[0] + sbv[cc] - 2.f * (acc[0][cc].x + acc[0][cc].y)) * C2;
          lo.y = (sa8[1] + sbv[cc] - 2.f * (acc[1][cc].x + acc[1][cc].y)) * C2;
          lo.z = (sa8[2] + sbv[cc] - 2.f * (acc[2][cc].x + acc[2][cc].y)) * C2;
          lo.w = (sa8[3] + sbv[cc] - 2.f * (acc[3][cc].x + acc[3][cc].y)) * C2;
          hi.x = (sa8[4] + sbv[cc] - 2.f * (acc[4][cc].x + acc[4][cc].y)) * C2;
          hi.y = (sa8[5] + sbv[cc] - 2.f * (acc[5][cc].x + acc[5][cc].y)) * C2;
          hi.z = (sa8[6] + sbv[cc] - 2.f * (acc[6][cc].x + acc[6][cc].y)) * C2;
          hi.w = (sa8[7] + sbv[cc] - 2.f * (acc[7][cc].x + acc[7][cc].y)) * C2;
          float* dp = &DtW[(4 * cg + cc) * DCS + 8 * rg];
          *(float4*)dp = lo;
          *(float4*)(dp + 4) = hi;
        }
      }
    }
  } else {
    // =====================  DP (consumer) waves  ===========================
    const int d = w - NWAVE;                    // 0..5, owns rows 64d+1..64d+64
    const bool dActive = (64 * d < la);
    const int dn = (d + 1 < NWAVE) ? (d + 1) : 0;
    float leftR = BIGS;
    float* DtW = &Dt[d][0];

    for (int rr = 0; rr < NROUND2; ++rr) {
      __syncthreads();                           // S1
      const int p = rr - 1 - d;
      if ((unsigned)p < (unsigned)NPANEL && dActive && (32 * p < lb)) {
        float* bndR = &bnd[d][rr & 1][0];
        float* bndW = &bnd[dn][(rr + 1) & 1][0];
        const bool wr63 = (lane == 63) && (d + 1 < NWAVE) && (64 * (d + 1) < la);
        if (wr63) bndW[0] = leftR;

        float d0, d1, d2;
        {
          int j0 = (0 - lane) & 31, j1 = (1 - lane) & 31, j2 = (2 - lane) & 31;
          d0 = DtW[j0 * DCS + lane];
          d1 = DtW[j1 * DCS + lane];
          d2 = DtW[j2 * DCS + lane];
        }
        float cur = leftR;
        float extv = 0.f;
        float bq0[4] = {BIGS, BIGS, BIGS, BIGS}, bq1[4] = {BIGS, BIGS, BIGS, BIGS};
        if (d > 0) {
          float4 q0 = *(const float4*)&bndR[0];
          float4 q1 = *(const float4*)&bndR[4];
          bq0[0]=q0.x; bq0[1]=q0.y; bq0[2]=q0.z; bq0[3]=q0.w;
          bq1[0]=q1.x; bq1[1]=q1.y; bq1[2]=q1.z; bq1[3]=q1.w;
        }
        float s2;
        {
          float fix0 = (d == 0) ? ((p == 0) ? 0.f : BIGS) : bq0[0];
          s2 = (lane == 0) ? fix0 : cur;
        }
        const bool extRound = (d == wt) && (rr == rstar2);

#define STEP(T, BUPRAW) do {                                                \
        float s1 = wshr1f(cur);                                             \
        if (lane == 0) s1 = (d == 0) ? BIGS : (BUPRAW);                     \
        int jl = (T) - lane;                                                \
        float dv = d0; d0 = d1; d1 = d2;                                    \
        { int jc = ((T) + 3 - lane) & 31;                                   \
          d2 = DtW[jc * DCS + lane]; }                                      \
        float m = fminf(s2, fminf(s1, cur));                                \
        float e = fexp2(m - s2) + fexp2(m - s1) + fexp2(m - cur);           \
        float val = dv + m - flog2(e);                                      \
        s2 = s1;                                                            \
        if (extRound && tstar == (T) && lane == it) extv = val;             \
        if ((unsigned)jl < 32u) {                                           \
          cur = val;                                                        \
          if (wr63) bndW[jl + 1] = val;                                     \
        }                                                                   \
      } while (0)

        for (int tq = 0; tq < 24; ++tq) {
          const int tb = tq * 4;
          float bq2[4];
          {
            int off = tb + 8; off = off > 32 ? 32 : off;
            float4 q = *(const float4*)&bndR[off];
            bq2[0]=q.x; bq2[1]=q.y; bq2[2]=q.z; bq2[3]=q.w;
          }
          STEP(tb + 0, bq0[1]);
          STEP(tb + 1, bq0[2]);
          STEP(tb + 2, bq0[3]);
          STEP(tb + 3, bq1[0]);
          bq0[0]=bq1[0]; bq0[1]=bq1[1]; bq0[2]=bq1[2]; bq0[3]=bq1[3];
          bq1[0]=bq2[0]; bq1[1]=bq2[1]; bq1[2]=bq2[2]; bq1[3]=bq2[3];
        }
#undef STEP
        if (extRound && lane == it) dist[p_id] = extv * scale;
        leftR = cur;
      }
      __syncthreads();                           // S2
    }
  }
}

// ---------------------------------------------------------------------------
// Loss reduction over 16 windows (validated rounds 1-7).
// ---------------------------------------------------------------------------
__device__ __forceinline__ float median5(const float* v) {
#pragma unroll
  for (int i = 0; i < 5; ++i) {
    int c = 0;
#pragma unroll
    for (int j = 0; j < 5; ++j)
      c += (v[j] < v[i]) || ((v[j] == v[i]) && (j < i));
    if (c == 2) return v[i];
  }
  return v[0];
}

__global__ void loss_kernel(const float* __restrict__ dist, float* __restrict__ out) {
  __shared__ float acc[NWIN];
  const int w = threadIdx.x;
  if (w < NWIN) {
    float dg[5], dn[10];
#pragma unroll
    for (int g = 0; g < 5; ++g)  dg[g] = dist[w * PERW + g];
#pragma unroll
    for (int n = 0; n < 10; ++n) dn[n] = dist[w * PERW + 5 + n];

    float lk = 0.f; int nz = 0;
#pragma unroll
    for (int g = 0; g < 5; ++g)
#pragma unroll
      for (int n = 0; n < 10; ++n) {
        float t = dg[g] + 1.0f - dn[n];
        if (t > 0.f) { lk += t; ++nz; }
      }
    float lv = lk / (1.0f + (float)nz);

    float sp = 0.f;
#pragma unroll
    for (int g = 0; g < 5; ++g) sp += dg[g];
    float only_pos = sp * (0.01f / 5.0f);

    float mg = median5(dg);
    float ms = median5(dn);

    int err = 0;
#pragma unroll
    for (int g = 0; g < 5; ++g) {
      err += ((dg[g] < mg) && (dn[g] < mg));
      err += ((dg[g] > ms) && (dn[g] > ms));
      err += ((dg[g] < mg) && (dn[5 + g] < mg));
      err += ((dg[g] > ms) && (dn[5 + g] > ms));
    }
    float offset = (float)err * (1.0f / 50.0f);

    acc[w] = lv + only_pos + offset;
  }
  __syncthreads();
  if (w == 0) {
    float s = 0.f;
#pragma unroll
    for (int i = 0; i < NWIN; ++i) s += acc[i];
    out[0] = s / (float)NWIN;
  }
}

// ---------------------------------------------------------------------------
extern "C" void kernel_launch(void* const* d_in, const int* in_sizes, int n_in,
                              void* d_out, int out_size, void* d_ws, size_t ws_size,
                              hipStream_t stream) {
  const float* data = (const float*)d_in[0];
  const int* lens   = (const int*)d_in[1];
  float* dist = (float*)d_ws;

  sdtw_kernel<<<NPAIR, 768, 0, stream>>>(data, lens, dist);
  loss_kernel<<<1, 64, 0, stream>>>(dist, (float*)d_out);
}

// Round 9
// 272.001 us; speedup vs baseline: 1.1340x; 1.1340x over previous
//
#include <hip/hip_runtime.h>

#define LQ 384
#define DF 64
#define NWIN 16
#define PERW 15      // NG + NF
#define STEPW 16     // 1 + NG + NF
#define NPAIR 240    // NWIN * PERW
#define NWAVE 6      // row-slabs (producer waves and consumer waves each)
#define PW 32        // panel width (cols per round)
#define NPANEL 12    // 384 / PW
#define NROUND2 18   // NPANEL + NWAVE - 1 + 1 (producer lead)
#define DCS 68       // D-tile column stride (col-major [32 cols][68])
#define C2  0.28853900817779268f   // 1/(5*ln2)  (pre-scale: R' = R*C2)
#define L2C 3.4657359027997265f    // 5*ln2      (unscale at extraction)
#define BIGS (1e9f * C2)           // BIG in scaled domain

__device__ __forceinline__ float fexp2(float x) { return __builtin_amdgcn_exp2f(x); }
__device__ __forceinline__ float flog2(float x) { return __builtin_amdgcn_logf(x); }

// wave_shr:1 -- lane l gets lane l-1's value (VALU pipe). lane0 keeps own (fixed up).
__device__ __forceinline__ float wshr1f(float x) {
  int xi = __float_as_int(x);
  return __int_as_float(__builtin_amdgcn_update_dpp(xi, xi, 0x138, 0xF, 0xF, false));
}

// ---------------------------------------------------------------------------
// Producer-consumer soft-DTW (r7 structure, 1 barrier/round, double-buffered
// Dt). Producer K-loop is software-pipelined: registers double-buffer the
// next K-chunk's A/B global loads under the current chunk's FMAs.
// ---------------------------------------------------------------------------
__global__ __launch_bounds__(768, 3) void sdtw_kernel(const float* __restrict__ data,
                                                      const int* __restrict__ lens,
                                                      float* __restrict__ dist) {
  __shared__ __align__(16) float Dt[2][NWAVE][32 * DCS];   // 104448 B (D*C2, col-major)
  __shared__ __align__(16) float sqA[LQ];                  // 1536 B
  __shared__ __align__(16) float sqB[LQ];                  // 1536 B
  __shared__ __align__(16) float bnd[NWAVE][2][36];        // 1728 B  (109248 total)

  const int p_id = blockIdx.x;
  const int wwin = p_id / PERW;
  const int o = p_id - wwin * PERW;
  const int aRow = wwin * STEPW;
  const int bRow = aRow + 1 + o;
  const int la = lens[aRow];
  const int lb = lens[bRow];
  const int tid = threadIdx.x;
  const int w = tid >> 6;        // 0..11
  const int lane = tid & 63;

  const float* __restrict__ A  = data + (size_t)aRow * LQ * DF;
  const float* __restrict__ Bp = data + (size_t)bRow * LQ * DF;

  // ---- staging: threads 0..383 -> sqA; threads 384..767 -> sqB ----
  {
    const float* src = (tid < LQ) ? (A + (size_t)tid * DF) : (Bp + (size_t)(tid - LQ) * DF);
    const float4* S4 = (const float4*)src;
    float s = 0.f;
#pragma unroll
    for (int k = 0; k < 16; ++k) {
      float4 v = S4[k];
      s = fmaf(v.x, v.x, s); s = fmaf(v.y, v.y, s);
      s = fmaf(v.z, v.z, s); s = fmaf(v.w, v.w, s);
    }
    if (tid < LQ) sqA[tid] = s; else sqB[tid - LQ] = s;
  }
  __syncthreads();

  // extraction target: R[la][lb] at DP wave wt, lane it, panel pt
  const int wt = (la - 1) >> 6;
  const int it = (la - 1) & 63;
  const int pt = (lb - 1) >> 5;
  const int tstar = it + ((lb - 1) & 31);
  const int rstar2 = wt + pt + 1;               // consumer round index
  const float scale = L2C / (float)(la + lb);

  if (w < NWAVE) {
    // =====================  GEMM (producer) waves  =========================
    const int g = w;
    const int rg = lane >> 3, cg = lane & 7;    // 8 rows x 4 cols per lane
    const bool gActive = (64 * g < la);
    const float4* A4g = (const float4*)(A + (size_t)(64 * g + 8 * rg) * DF);
    float sa8[8];
    *(float4*)&sa8[0] = *(const float4*)&sqA[64 * g + 8 * rg];
    *(float4*)&sa8[4] = *(const float4*)&sqA[64 * g + 8 * rg + 4];

    for (int rr = 0; rr < NROUND2; ++rr) {
      __syncthreads();
      const int p = rr - g;
      if ((unsigned)p < (unsigned)NPANEL && gActive && (32 * p < lb)) {
        float* DtW = &Dt[rr & 1][g][0];
        const float4* B4g = (const float4*)(Bp + (size_t)(PW * p + 4 * cg) * DF);

        float acc[8][4];
#pragma unroll
        for (int a_ = 0; a_ < 8; ++a_)
#pragma unroll
          for (int b_ = 0; b_ < 4; ++b_) acc[a_][b_] = 0.f;

        // software-pipelined K-loop: prefetch chunk kk+1 under chunk kk's FMAs
        float4 cA[8], cB[4];
#pragma unroll
        for (int rrr = 0; rrr < 8; ++rrr) cA[rrr] = A4g[rrr * 16];
#pragma unroll
        for (int cc = 0; cc < 4; ++cc) cB[cc] = B4g[cc * 16];

#pragma unroll
        for (int kk = 0; kk < 16; ++kk) {
          float4 nA[8], nB[4];
          if (kk < 15) {
#pragma unroll
            for (int rrr = 0; rrr < 8; ++rrr) nA[rrr] = A4g[rrr * 16 + kk + 1];
#pragma unroll
            for (int cc = 0; cc < 4; ++cc) nB[cc] = B4g[cc * 16 + kk + 1];
          }
#pragma unroll
          for (int rrr = 0; rrr < 8; ++rrr)
#pragma unroll
            for (int cc = 0; cc < 4; ++cc) {
              acc[rrr][cc] = fmaf(cA[rrr].x, cB[cc].x, acc[rrr][cc]);
              acc[rrr][cc] = fmaf(cA[rrr].y, cB[cc].y, acc[rrr][cc]);
              acc[rrr][cc] = fmaf(cA[rrr].z, cB[cc].z, acc[rrr][cc]);
              acc[rrr][cc] = fmaf(cA[rrr].w, cB[cc].w, acc[rrr][cc]);
            }
          if (kk < 15) {
#pragma unroll
            for (int rrr = 0; rrr < 8; ++rrr) cA[rrr] = nA[rrr];
#pragma unroll
            for (int cc = 0; cc < 4; ++cc) cB[cc] = nB[cc];
          }
        }
        // epilogue: D' = (sqA + sqB - 2*dot) * C2, col-major store
        float4 sb = *(const float4*)&sqB[PW * p + 4 * cg];
        float sbv[4] = {sb.x, sb.y, sb.z, sb.w};
#pragma unroll
        for (int cc = 0; cc < 4; ++cc) {
          float4 lo, hi;
          lo.x = (sa8[0] + sbv[cc] - 2.f * acc[0][cc]) * C2;
          lo.y = (sa8[1] + sbv[cc] - 2.f * acc[1][cc]) * C2;
          lo.z = (sa8[2] + sbv[cc] - 2.f * acc[2][cc]) * C2;
          lo.w = (sa8[3] + sbv[cc] - 2.f * acc[3][cc]) * C2;
          hi.x = (sa8[4] + sbv[cc] - 2.f * acc[4][cc]) * C2;
          hi.y = (sa8[5] + sbv[cc] - 2.f * acc[5][cc]) * C2;
          hi.z = (sa8[6] + sbv[cc] - 2.f * acc[6][cc]) * C2;
          hi.w = (sa8[7] + sbv[cc] - 2.f * acc[7][cc]) * C2;
          float* dp = &DtW[(4 * cg + cc) * DCS + 8 * rg];
          *(float4*)dp = lo;
          *(float4*)(dp + 4) = hi;
        }
      }
    }
  } else {
    // =====================  DP (consumer) waves  ===========================
    const int d = w - NWAVE;                    // 0..5, owns rows 64d+1..64d+64
    const bool dActive = (64 * d < la);
    const int dn = (d + 1 < NWAVE) ? (d + 1) : 0;
    float leftR = BIGS;

    for (int rr = 0; rr < NROUND2; ++rr) {
      __syncthreads();
      const int p = rr - 1 - d;
      if ((unsigned)p < (unsigned)NPANEL && dActive && (32 * p < lb)) {
        float* DtW = &Dt[(rr - 1) & 1][d][0];

        float* bndR = &bnd[d][rr & 1][0];
        float* bndW = &bnd[dn][(rr + 1) & 1][0];
        const bool wr63 = (lane == 63) && (d + 1 < NWAVE) && (64 * (d + 1) < la);
        if (wr63) bndW[0] = leftR;

        float d0, d1, d2;
        {
          int j0 = (0 - lane) & 31, j1 = (1 - lane) & 31, j2 = (2 - lane) & 31;
          d0 = DtW[j0 * DCS + lane];
          d1 = DtW[j1 * DCS + lane];
          d2 = DtW[j2 * DCS + lane];
        }
        float cur = leftR;
        float extv = 0.f;
        float bq0[4] = {BIGS, BIGS, BIGS, BIGS}, bq1[4] = {BIGS, BIGS, BIGS, BIGS};
        if (d > 0) {
          float4 q0 = *(const float4*)&bndR[0];
          float4 q1 = *(const float4*)&bndR[4];
          bq0[0]=q0.x; bq0[1]=q0.y; bq0[2]=q0.z; bq0[3]=q0.w;
          bq1[0]=q1.x; bq1[1]=q1.y; bq1[2]=q1.z; bq1[3]=q1.w;
        }
        float s2;
        {
          float fix0 = (d == 0) ? ((p == 0) ? 0.f : BIGS) : bq0[0];
          s2 = (lane == 0) ? fix0 : cur;
        }
        const bool extRound = (d == wt) && (rr == rstar2);

#define STEP(T, BUPRAW) do {                                                \
        float s1 = wshr1f(cur);                                             \
        if (lane == 0) s1 = (d == 0) ? BIGS : (BUPRAW);                     \
        int jl = (T) - lane;                                                \
        float dv = d0; d0 = d1; d1 = d2;                                    \
        { int jc = ((T) + 3 - lane) & 31;                                   \
          d2 = DtW[jc * DCS + lane]; }                                      \
        float m = fminf(s2, fminf(s1, cur));                                \
        float e = fexp2(m - s2) + fexp2(m - s1) + fexp2(m - cur);           \
        float val = dv + m - flog2(e);                                      \
        s2 = s1;                                                            \
        if (extRound && tstar == (T) && lane == it) extv = val;             \
        if ((unsigned)jl < 32u) {                                           \
          cur = val;                                                        \
          if (wr63) bndW[jl + 1] = val;                                     \
        }                                                                   \
      } while (0)

        for (int tq = 0; tq < 24; ++tq) {
          const int tb = tq * 4;
          float bq2[4];
          {
            int off = tb + 8; off = off > 32 ? 32 : off;
            float4 q = *(const float4*)&bndR[off];
            bq2[0]=q.x; bq2[1]=q.y; bq2[2]=q.z; bq2[3]=q.w;
          }
          STEP(tb + 0, bq0[1]);
          STEP(tb + 1, bq0[2]);
          STEP(tb + 2, bq0[3]);
          STEP(tb + 3, bq1[0]);
          bq0[0]=bq1[0]; bq0[1]=bq1[1]; bq0[2]=bq1[2]; bq0[3]=bq1[3];
          bq1[0]=bq2[0]; bq1[1]=bq2[1]; bq1[2]=bq2[2]; bq1[3]=bq2[3];
        }
#undef STEP
        if (extRound && lane == it) dist[p_id] = extv * scale;
        leftR = cur;
      }
    }
  }
}

// ---------------------------------------------------------------------------
// Loss reduction over 16 windows (validated rounds 1-8).
// ---------------------------------------------------------------------------
__device__ __forceinline__ float median5(const float* v) {
#pragma unroll
  for (int i = 0; i < 5; ++i) {
    int c = 0;
#pragma unroll
    for (int j = 0; j < 5; ++j)
      c += (v[j] < v[i]) || ((v[j] == v[i]) && (j < i));
    if (c == 2) return v[i];
  }
  return v[0];
}

__global__ void loss_kernel(const float* __restrict__ dist, float* __restrict__ out) {
  __shared__ float acc[NWIN];
  const int w = threadIdx.x;
  if (w < NWIN) {
    float dg[5], dn[10];
#pragma unroll
    for (int g = 0; g < 5; ++g)  dg[g] = dist[w * PERW + g];
#pragma unroll
    for (int n = 0; n < 10; ++n) dn[n] = dist[w * PERW + 5 + n];

    float lk = 0.f; int nz = 0;
#pragma unroll
    for (int g = 0; g < 5; ++g)
#pragma unroll
      for (int n = 0; n < 10; ++n) {
        float t = dg[g] + 1.0f - dn[n];
        if (t > 0.f) { lk += t; ++nz; }
      }
    float lv = lk / (1.0f + (float)nz);

    float sp = 0.f;
#pragma unroll
    for (int g = 0; g < 5; ++g) sp += dg[g];
    float only_pos = sp * (0.01f / 5.0f);

    float mg = median5(dg);
    float ms = median5(dn);

    int err = 0;
#pragma unroll
    for (int g = 0; g < 5; ++g) {
      err += ((dg[g] < mg) && (dn[g] < mg));
      err += ((dg[g] > ms) && (dn[g] > ms));
      err += ((dg[g] < mg) && (dn[5 + g] < mg));
      err += ((dg[g] > ms) && (dn[5 + g] > ms));
    }
    float offset = (float)err * (1.0f / 50.0f);

    acc[w] = lv + only_pos + offset;
  }
  __syncthreads();
  if (w == 0) {
    float s = 0.f;
#pragma unroll
    for (int i = 0; i < NWIN; ++i) s += acc[i];
    out[0] = s / (float)NWIN;
  }
}

// ---------------------------------------------------------------------------
extern "C" void kernel_launch(void* const* d_in, const int* in_sizes, int n_in,
                              void* d_out, int out_size, void* d_ws, size_t ws_size,
                              hipStream_t stream) {
  const float* data = (const float*)d_in[0];
  const int* lens   = (const int*)d_in[1];
  float* dist = (float*)d_ws;

  sdtw_kernel<<<NPAIR, 768, 0, stream>>>(data, lens, dist);
  loss_kernel<<<1, 64, 0, stream>>>(dist, (float*)d_out);
}

// Round 10
// 214.866 us; speedup vs baseline: 1.4356x; 1.2659x over previous
//
#include <hip/hip_runtime.h>
#include <hip/hip_fp16.h>

#define LQ 384
#define DF 64
#define NWIN 16
#define PERW 15      // NG + NF
#define STEPW 16     // 1 + NG + NF
#define NPAIR 240    // NWIN * PERW
#define NWAVE 6      // row-slabs (producer waves and consumer waves each)
#define PW 32        // panel width (cols per round)
#define NPANEL 12    // 384 / PW
#define NROUND2 18   // NPANEL + NWAVE - 1 + 1 (producer lead)
#define BST 66       // B LDS row stride (floats)
#define DCS2 72      // fp16 D-tile column stride (halfs); 72*2=144 B, 16B-aligned
#define C2  0.28853900817779268f   // 1/(5*ln2)  (pre-scale: R' = R*C2)
#define L2C 3.4657359027997265f    // 5*ln2      (unscale at extraction)
#define BIGS (1e9f * C2)           // BIG in scaled domain

typedef float v2f __attribute__((ext_vector_type(2)));

__device__ __forceinline__ float fexp2(float x) { return __builtin_amdgcn_exp2f(x); }
__device__ __forceinline__ float flog2(float x) { return __builtin_amdgcn_logf(x); }

// wave_shr:1 -- lane l gets lane l-1's value (VALU pipe). lane0 keeps own (fixed up).
__device__ __forceinline__ float wshr1f(float x) {
  int xi = __float_as_int(x);
  return __int_as_float(__builtin_amdgcn_update_dpp(xi, xi, 0x138, 0xF, 0xF, false));
}

// ---------------------------------------------------------------------------
// Producer-consumer soft-DTW (r7 structure: 1 barrier/round, double-buffered
// D tiles). Producers run the r3-validated GEMM (B from LDS, A via L1) and
// store D' in fp16 (RTN) so Bsh + double Dt fit in 160 KB LDS.
// ---------------------------------------------------------------------------
__global__ __launch_bounds__(768, 3) void sdtw_kernel(const float* __restrict__ data,
                                                      const int* __restrict__ lens,
                                                      float* __restrict__ dist) {
  __shared__ __align__(16) float  Bsh[LQ * BST];             // 101376 B
  __shared__ __align__(16) __half DtH[2][NWAVE][32 * DCS2];  // 55296 B (D*C2 in fp16)
  __shared__ __align__(16) float  sqA[LQ];                   // 1536 B
  __shared__ __align__(16) float  sqB[LQ];                   // 1536 B
  __shared__ __align__(16) float  bnd[NWAVE][2][36];         // 1728 B  (161472 total)

  const int p_id = blockIdx.x;
  const int wwin = p_id / PERW;
  const int o = p_id - wwin * PERW;
  const int aRow = wwin * STEPW;
  const int bRow = aRow + 1 + o;
  const int la = lens[aRow];
  const int lb = lens[bRow];
  const int tid = threadIdx.x;
  const int w = tid >> 6;        // 0..11
  const int lane = tid & 63;

  const float* __restrict__ A  = data + (size_t)aRow * LQ * DF;
  const float* __restrict__ Bp = data + (size_t)bRow * LQ * DF;

  // ---- stage B into LDS (768 threads); sqA (threads 0..383 from global) ----
  {
    const float4* B4 = (const float4*)Bp;
    for (int q = tid; q < LQ * 16; q += 768) {
      float4 v = B4[q];
      int row = q >> 4, c4 = (q & 15) << 2;
      float* dst = &Bsh[row * BST + c4];
      ((float2*)dst)[0] = make_float2(v.x, v.y);
      ((float2*)dst)[1] = make_float2(v.z, v.w);
    }
  }
  if (tid < LQ) {
    const float4* A4 = (const float4*)(A + (size_t)tid * DF);
    float s = 0.f;
#pragma unroll
    for (int k = 0; k < 16; ++k) {
      float4 v = A4[k];
      s = fmaf(v.x, v.x, s); s = fmaf(v.y, v.y, s);
      s = fmaf(v.z, v.z, s); s = fmaf(v.w, v.w, s);
    }
    sqA[tid] = s;
  }
  __syncthreads();
  if (tid < LQ) {
    float s = 0.f;
    const float2* row = (const float2*)&Bsh[tid * BST];
#pragma unroll
    for (int k = 0; k < 32; ++k) { float2 v = row[k]; s = fmaf(v.x, v.x, s); s = fmaf(v.y, v.y, s); }
    sqB[tid] = s;
  }
  __syncthreads();

  // extraction target: R[la][lb] at DP wave wt, lane it, panel pt
  const int wt = (la - 1) >> 6;
  const int it = (la - 1) & 63;
  const int pt = (lb - 1) >> 5;
  const int tstar = it + ((lb - 1) & 31);
  const int rstar2 = wt + pt + 1;               // consumer round index
  const float scale = L2C / (float)(la + lb);

  if (w < NWAVE) {
    // =====================  GEMM (producer) waves  =========================
    const int g = w;
    const int rg = lane >> 3, cg = lane & 7;    // 8 rows x 4 cols per lane
    const bool gActive = (64 * g < la);
    const float4* A4g = (const float4*)(A + (size_t)(64 * g + 8 * rg) * DF);
    float sa8[8];
    *(float4*)&sa8[0] = *(const float4*)&sqA[64 * g + 8 * rg];
    *(float4*)&sa8[4] = *(const float4*)&sqA[64 * g + 8 * rg + 4];

    for (int rr = 0; rr < NROUND2; ++rr) {
      __syncthreads();
      const int p = rr - g;
      if ((unsigned)p < (unsigned)NPANEL && gActive && (32 * p < lb)) {
        __half* DtW = &DtH[rr & 1][g][0];
        // ----- r3-validated GEMM: B from LDS (float2), A from global/L1 -----
        v2f acc[8][4];
#pragma unroll
        for (int a_ = 0; a_ < 8; ++a_)
#pragma unroll
          for (int b_ = 0; b_ < 4; ++b_) { acc[a_][b_].x = 0.f; acc[a_][b_].y = 0.f; }
        const float* Bb = &Bsh[(PW * p + 4 * cg) * BST];
#pragma unroll
        for (int kk = 0; kk < 16; ++kk) {
          v2f b0[4], b1[4];
#pragma unroll
          for (int cc = 0; cc < 4; ++cc) {
            b0[cc] = *(const v2f*)&Bb[cc * BST + 4 * kk];
            b1[cc] = *(const v2f*)&Bb[cc * BST + 4 * kk + 2];
          }
#pragma unroll
          for (int rrr = 0; rrr < 8; ++rrr) {
            float4 v = A4g[rrr * 16 + kk];
            v2f a0, a1;
            a0.x = v.x; a0.y = v.y; a1.x = v.z; a1.y = v.w;
#pragma unroll
            for (int cc = 0; cc < 4; ++cc) {
              acc[rrr][cc] = __builtin_elementwise_fma(a0, b0[cc], acc[rrr][cc]);
              acc[rrr][cc] = __builtin_elementwise_fma(a1, b1[cc], acc[rrr][cc]);
            }
          }
        }
        // ----- epilogue: D' = (sqA + sqB - 2*dot)*C2 -> fp16 RTN, b128 store --
        float4 sb = *(const float4*)&sqB[PW * p + 4 * cg];
        float sbv[4] = {sb.x, sb.y, sb.z, sb.w};
#pragma unroll
        for (int cc = 0; cc < 4; ++cc) {
          float v0 = (sa8[0] + sbv[cc] - 2.f * (acc[0][cc].x + acc[0][cc].y)) * C2;
          float v1 = (sa8[1] + sbv[cc] - 2.f * (acc[1][cc].x + acc[1][cc].y)) * C2;
          float v2 = (sa8[2] + sbv[cc] - 2.f * (acc[2][cc].x + acc[2][cc].y)) * C2;
          float v3 = (sa8[3] + sbv[cc] - 2.f * (acc[3][cc].x + acc[3][cc].y)) * C2;
          float v4 = (sa8[4] + sbv[cc] - 2.f * (acc[4][cc].x + acc[4][cc].y)) * C2;
          float v5 = (sa8[5] + sbv[cc] - 2.f * (acc[5][cc].x + acc[5][cc].y)) * C2;
          float v6 = (sa8[6] + sbv[cc] - 2.f * (acc[6][cc].x + acc[6][cc].y)) * C2;
          float v7 = (sa8[7] + sbv[cc] - 2.f * (acc[7][cc].x + acc[7][cc].y)) * C2;
          uint h0 = __half_as_ushort(__float2half(v0));
          uint h1 = __half_as_ushort(__float2half(v1));
          uint h2 = __half_as_ushort(__float2half(v2));
          uint h3 = __half_as_ushort(__float2half(v3));
          uint h4 = __half_as_ushort(__float2half(v4));
          uint h5 = __half_as_ushort(__float2half(v5));
          uint h6 = __half_as_ushort(__float2half(v6));
          uint h7 = __half_as_ushort(__float2half(v7));
          uint4 q;
          q.x = h0 | (h1 << 16);
          q.y = h2 | (h3 << 16);
          q.z = h4 | (h5 << 16);
          q.w = h6 | (h7 << 16);
          *(uint4*)&DtW[(4 * cg + cc) * DCS2 + 8 * rg] = q;
        }
      }
    }
  } else {
    // =====================  DP (consumer) waves  ===========================
    const int d = w - NWAVE;                    // 0..5, owns rows 64d+1..64d+64
    const bool dActive = (64 * d < la);
    const int dn = (d + 1 < NWAVE) ? (d + 1) : 0;
    float leftR = BIGS;

    for (int rr = 0; rr < NROUND2; ++rr) {
      __syncthreads();
      const int p = rr - 1 - d;
      if ((unsigned)p < (unsigned)NPANEL && dActive && (32 * p < lb)) {
        const __half* DtW = &DtH[(rr - 1) & 1][d][0];

        float* bndR = &bnd[d][rr & 1][0];
        float* bndW = &bnd[dn][(rr + 1) & 1][0];
        const bool wr63 = (lane == 63) && (d + 1 < NWAVE) && (64 * (d + 1) < la);
        if (wr63) bndW[0] = leftR;

        float d0, d1, d2;
        {
          int j0 = (0 - lane) & 31, j1 = (1 - lane) & 31, j2 = (2 - lane) & 31;
          d0 = __half2float(DtW[j0 * DCS2 + lane]);
          d1 = __half2float(DtW[j1 * DCS2 + lane]);
          d2 = __half2float(DtW[j2 * DCS2 + lane]);
        }
        float cur = leftR;
        float extv = 0.f;
        float bq0[4] = {BIGS, BIGS, BIGS, BIGS}, bq1[4] = {BIGS, BIGS, BIGS, BIGS};
        if (d > 0) {
          float4 q0 = *(const float4*)&bndR[0];
          float4 q1 = *(const float4*)&bndR[4];
          bq0[0]=q0.x; bq0[1]=q0.y; bq0[2]=q0.z; bq0[3]=q0.w;
          bq1[0]=q1.x; bq1[1]=q1.y; bq1[2]=q1.z; bq1[3]=q1.w;
        }
        float s2;
        {
          float fix0 = (d == 0) ? ((p == 0) ? 0.f : BIGS) : bq0[0];
          s2 = (lane == 0) ? fix0 : cur;
        }
        const bool extRound = (d == wt) && (rr == rstar2);

#define STEP(T, BUPRAW) do {                                                \
        float s1 = wshr1f(cur);                                             \
        if (lane == 0) s1 = (d == 0) ? BIGS : (BUPRAW);                     \
        int jl = (T) - lane;                                                \
        float dv = d0; d0 = d1; d1 = d2;                                    \
        { int jc = ((T) + 3 - lane) & 31;                                   \
          d2 = __half2float(DtW[jc * DCS2 + lane]); }                       \
        float m = fminf(s2, fminf(s1, cur));                                \
        float e = fexp2(m - s2) + fexp2(m - s1) + fexp2(m - cur);           \
        float val = dv + m - flog2(e);                                      \
        s2 = s1;                                                            \
        if (extRound && tstar == (T) && lane == it) extv = val;             \
        if ((unsigned)jl < 32u) {                                           \
          cur = val;                                                        \
          if (wr63) bndW[jl + 1] = val;                                     \
        }                                                                   \
      } while (0)

        for (int tq = 0; tq < 24; ++tq) {
          const int tb = tq * 4;
          float bq2[4];
          {
            int off = tb + 8; off = off > 32 ? 32 : off;
            float4 q = *(const float4*)&bndR[off];
            bq2[0]=q.x; bq2[1]=q.y; bq2[2]=q.z; bq2[3]=q.w;
          }
          STEP(tb + 0, bq0[1]);
          STEP(tb + 1, bq0[2]);
          STEP(tb + 2, bq0[3]);
          STEP(tb + 3, bq1[0]);
          bq0[0]=bq1[0]; bq0[1]=bq1[1]; bq0[2]=bq1[2]; bq0[3]=bq1[3];
          bq1[0]=bq2[0]; bq1[1]=bq2[1]; bq1[2]=bq2[2]; bq1[3]=bq2[3];
        }
#undef STEP
        if (extRound && lane == it) dist[p_id] = extv * scale;
        leftR = cur;
      }
    }
  }
}

// ---------------------------------------------------------------------------
// Loss reduction over 16 windows (validated rounds 1-9).
// ---------------------------------------------------------------------------
__device__ __forceinline__ float median5(const float* v) {
#pragma unroll
  for (int i = 0; i < 5; ++i) {
    int c = 0;
#pragma unroll
    for (int j = 0; j < 5; ++j)
      c += (v[j] < v[i]) || ((v[j] == v[i]) && (j < i));
    if (c == 2) return v[i];
  }
  return v[0];
}

__global__ void loss_kernel(const float* __restrict__ dist, float* __restrict__ out) {
  __shared__ float acc[NWIN];
  const int w = threadIdx.x;
  if (w < NWIN) {
    float dg[5], dn[10];
#pragma unroll
    for (int g = 0; g < 5; ++g)  dg[g] = dist[w * PERW + g];
#pragma unroll
    for (int n = 0; n < 10; ++n) dn[n] = dist[w * PERW + 5 + n];

    float lk = 0.f; int nz = 0;
#pragma unroll
    for (int g = 0; g < 5; ++g)
#pragma unroll
      for (int n = 0; n < 10; ++n) {
        float t = dg[g] + 1.0f - dn[n];
        if (t > 0.f) { lk += t; ++nz; }
      }
    float lv = lk / (1.0f + (float)nz);

    float sp = 0.f;
#pragma unroll
    for (int g = 0; g < 5; ++g) sp += dg[g];
    float only_pos = sp * (0.01f / 5.0f);

    float mg = median5(dg);
    float ms = median5(dn);

    int err = 0;
#pragma unroll
    for (int g = 0; g < 5; ++g) {
      err += ((dg[g] < mg) && (dn[g] < mg));
      err += ((dg[g] > ms) && (dn[g] > ms));
      err += ((dg[g] < mg) && (dn[5 + g] < mg));
      err += ((dg[g] > ms) && (dn[5 + g] > ms));
    }
    float offset = (float)err * (1.0f / 50.0f);

    acc[w] = lv + only_pos + offset;
  }
  __syncthreads();
  if (w == 0) {
    float s = 0.f;
#pragma unroll
    for (int i = 0; i < NWIN; ++i) s += acc[i];
    out[0] = s / (float)NWIN;
  }
}

// ---------------------------------------------------------------------------
extern "C" void kernel_launch(void* const* d_in, const int* in_sizes, int n_in,
                              void* d_out, int out_size, void* d_ws, size_t ws_size,
                              hipStream_t stream) {
  const float* data = (const float*)d_in[0];
  const int* lens   = (const int*)d_in[1];
  float* dist = (float*)d_ws;

  sdtw_kernel<<<NPAIR, 768, 0, stream>>>(data, lens, dist);
  loss_kernel<<<1, 64, 0, stream>>>(dist, (float*)d_out);
}

// Round 11
// 167.086 us; speedup vs baseline: 1.8461x; 1.2860x over previous
//
#include <hip/hip_runtime.h>
#include <hip/hip_fp16.h>

#define LQ 384
#define DF 64
#define NWIN 16
#define PERW 15      // NG + NF
#define STEPW 16     // 1 + NG + NF
#define NPAIR 240    // NWIN * PERW
#define NWAVE 6      // row-slabs (producer waves and consumer waves each)
#define PW 32        // panel width (cols per round)
#define NPANEL 12    // 384 / PW
#define NROUND2 18   // NPANEL + NWAVE - 1 + 1 (producer lead)
#define BST 66       // B LDS row stride (floats)
#define DRS 36       // fp16 D-tile ROW stride (halfs); 72 B, 8B-aligned
#define C2  0.28853900817779268f   // 1/(5*ln2)  (pre-scale: R' = R*C2)
#define L2C 3.4657359027997265f    // 5*ln2      (unscale at extraction)
#define BIGS (1e9f * C2)           // BIG in scaled domain

typedef float v2f __attribute__((ext_vector_type(2)));

__device__ __forceinline__ float fexp2(float x) { return __builtin_amdgcn_exp2f(x); }
__device__ __forceinline__ float flog2(float x) { return __builtin_amdgcn_logf(x); }

// wave_shr:1 -- lane l gets lane l-1's value (VALU pipe). lane0 keeps own (fixed up).
__device__ __forceinline__ float wshr1f(float x) {
  int xi = __float_as_int(x);
  return __int_as_float(__builtin_amdgcn_update_dpp(xi, xi, 0x138, 0xF, 0xF, false));
}

// ---------------------------------------------------------------------------
// Producer-consumer soft-DTW (r7/r10 structure: 1 barrier/round, double-
// buffered fp16 D tiles). This round: the DP inner loop is pure register/VALU
// -- D panel preloaded per-lane ROTATED (register index = step, compile-time),
// boundary row via readlane with literal index. Zero LDS ops on the chain.
// ---------------------------------------------------------------------------
__global__ __launch_bounds__(768, 3) void sdtw_kernel(const float* __restrict__ data,
                                                      const int* __restrict__ lens,
                                                      float* __restrict__ dist) {
  __shared__ __align__(16) float  Bsh[LQ * BST];             // 101376 B
  __shared__ __align__(16) __half DtH[2][NWAVE][64 * DRS];   // 55296 B (D*C2, row-major)
  __shared__ __align__(16) float  sqA[LQ];                   // 1536 B
  __shared__ __align__(16) float  sqB[LQ];                   // 1536 B
  __shared__ __align__(16) float  bnd[NWAVE][2][36];         // 1728 B  (161472 total)

  const int p_id = blockIdx.x;
  const int wwin = p_id / PERW;
  const int o = p_id - wwin * PERW;
  const int aRow = wwin * STEPW;
  const int bRow = aRow + 1 + o;
  const int la = lens[aRow];
  const int lb = lens[bRow];
  const int tid = threadIdx.x;
  const int w = tid >> 6;        // 0..11
  const int lane = tid & 63;

  const float* __restrict__ A  = data + (size_t)aRow * LQ * DF;
  const float* __restrict__ Bp = data + (size_t)bRow * LQ * DF;

  // ---- stage B into LDS (768 threads); sqA (threads 0..383 from global) ----
  {
    const float4* B4 = (const float4*)Bp;
    for (int q = tid; q < LQ * 16; q += 768) {
      float4 v = B4[q];
      int row = q >> 4, c4 = (q & 15) << 2;
      float* dst = &Bsh[row * BST + c4];
      ((float2*)dst)[0] = make_float2(v.x, v.y);
      ((float2*)dst)[1] = make_float2(v.z, v.w);
    }
  }
  if (tid < LQ) {
    const float4* A4 = (const float4*)(A + (size_t)tid * DF);
    float s = 0.f;
#pragma unroll
    for (int k = 0; k < 16; ++k) {
      float4 v = A4[k];
      s = fmaf(v.x, v.x, s); s = fmaf(v.y, v.y, s);
      s = fmaf(v.z, v.z, s); s = fmaf(v.w, v.w, s);
    }
    sqA[tid] = s;
  }
  __syncthreads();
  if (tid < LQ) {
    float s = 0.f;
    const float2* row = (const float2*)&Bsh[tid * BST];
#pragma unroll
    for (int k = 0; k < 32; ++k) { float2 v = row[k]; s = fmaf(v.x, v.x, s); s = fmaf(v.y, v.y, s); }
    sqB[tid] = s;
  }
  __syncthreads();

  // extraction target: R[la][lb] at DP wave wt, lane it, panel pt
  const int wt = (la - 1) >> 6;
  const int it = (la - 1) & 63;
  const int pt = (lb - 1) >> 5;
  const int tstar = it + ((lb - 1) & 31);
  const int rstar2 = wt + pt + 1;               // consumer round index
  const float scale = L2C / (float)(la + lb);

  if (w < NWAVE) {
    // =====================  GEMM (producer) waves  =========================
    const int g = w;
    const int rg = lane >> 3, cg = lane & 7;    // 8 rows x 4 cols per lane
    const bool gActive = (64 * g < la);
    const float4* A4g = (const float4*)(A + (size_t)(64 * g + 8 * rg) * DF);
    float sa8[8];
    *(float4*)&sa8[0] = *(const float4*)&sqA[64 * g + 8 * rg];
    *(float4*)&sa8[4] = *(const float4*)&sqA[64 * g + 8 * rg + 4];

    for (int rr = 0; rr < NROUND2; ++rr) {
      __syncthreads();
      const int p = rr - g;
      if ((unsigned)p < (unsigned)NPANEL && gActive && (32 * p < lb)) {
        __half* DtW = &DtH[rr & 1][g][0];
        // ----- GEMM: B from LDS (float2), A from global/L1 (r3-validated) ---
        v2f acc[8][4];
#pragma unroll
        for (int a_ = 0; a_ < 8; ++a_)
#pragma unroll
          for (int b_ = 0; b_ < 4; ++b_) { acc[a_][b_].x = 0.f; acc[a_][b_].y = 0.f; }
        const float* Bb = &Bsh[(PW * p + 4 * cg) * BST];
#pragma unroll
        for (int kk = 0; kk < 16; ++kk) {
          v2f b0[4], b1[4];
#pragma unroll
          for (int cc = 0; cc < 4; ++cc) {
            b0[cc] = *(const v2f*)&Bb[cc * BST + 4 * kk];
            b1[cc] = *(const v2f*)&Bb[cc * BST + 4 * kk + 2];
          }
#pragma unroll
          for (int rrr = 0; rrr < 8; ++rrr) {
            float4 v = A4g[rrr * 16 + kk];
            v2f a0, a1;
            a0.x = v.x; a0.y = v.y; a1.x = v.z; a1.y = v.w;
#pragma unroll
            for (int cc = 0; cc < 4; ++cc) {
              acc[rrr][cc] = __builtin_elementwise_fma(a0, b0[cc], acc[rrr][cc]);
              acc[rrr][cc] = __builtin_elementwise_fma(a1, b1[cc], acc[rrr][cc]);
            }
          }
        }
        // ----- epilogue: D' = (sqA+sqB-2*dot)*C2 -> fp16 RTN, row-major b64 --
        float4 sb = *(const float4*)&sqB[PW * p + 4 * cg];
        float sbv[4] = {sb.x, sb.y, sb.z, sb.w};
        float vr[8][4];
#pragma unroll
        for (int cc = 0; cc < 4; ++cc) {
#pragma unroll
          for (int rrr = 0; rrr < 8; ++rrr)
            vr[rrr][cc] = (sa8[rrr] + sbv[cc] - 2.f * (acc[rrr][cc].x + acc[rrr][cc].y)) * C2;
        }
#pragma unroll
        for (int rrr = 0; rrr < 8; ++rrr) {
          uint h0 = __half_as_ushort(__float2half(vr[rrr][0]));
          uint h1 = __half_as_ushort(__float2half(vr[rrr][1]));
          uint h2 = __half_as_ushort(__float2half(vr[rrr][2]));
          uint h3 = __half_as_ushort(__float2half(vr[rrr][3]));
          uint2 q;
          q.x = h0 | (h1 << 16);
          q.y = h2 | (h3 << 16);
          *(uint2*)&DtW[(8 * rg + rrr) * DRS + 4 * cg] = q;   // 8B-aligned
        }
      }
    }
  } else {
    // =====================  DP (consumer) waves  ===========================
    const int d = w - NWAVE;                    // 0..5, owns rows 64d+1..64d+64
    const bool dActive = (64 * d < la);
    const int dn = (d + 1 < NWAVE) ? (d + 1) : 0;
    const int l5 = lane & 31;
    float leftR = BIGS;

    for (int rr = 0; rr < NROUND2; ++rr) {
      __syncthreads();
      const int p = rr - 1 - d;
      if ((unsigned)p < (unsigned)NPANEL && dActive && (32 * p < lb)) {
        const __half* DtW = &DtH[(rr - 1) & 1][d][0];

        float* bndR = &bnd[d][rr & 1][0];
        float* bndW = &bnd[dn][(rr + 1) & 1][0];
        const bool wr63 = (lane == 63) && (d + 1 < NWAVE) && (64 * (d + 1) < la);
        if (wr63) bndW[0] = leftR;

        // ---- preload D row, pre-rotated: position p holds col (p-lane)&31 --
        const __half* baseA = DtW + (lane * DRS - l5);
        const __half* baseB = baseA + 32;
        __half hv[32];
#pragma unroll
        for (int pp = 0; pp < 32; ++pp)
          hv[pp] = (pp < l5) ? baseB[pp] : baseA[pp];

        // ---- preload boundary row into one VGPR per lane -------------------
        float vbnd = BIGS;
        if (d > 0 && lane < 36) vbnd = bndR[lane];

        float cur = leftR;
        float extv = 0.f;
        float s2;
        {
          float b0 = __int_as_float(__builtin_amdgcn_readlane(__float_as_int(vbnd), 0));
          float fix0 = (d == 0) ? ((p == 0) ? 0.f : BIGS) : b0;
          s2 = (lane == 0) ? fix0 : cur;
        }
        const bool extRound = (d == wt) && (rr == rstar2);

#define STEP(T) do {                                                        \
        float s1 = wshr1f(cur);                                             \
        if ((T) < 32) {                                                     \
          float bup = __int_as_float(                                       \
              __builtin_amdgcn_readlane(__float_as_int(vbnd), (T) + 1));    \
          s1 = (lane == 0) ? bup : s1;                                      \
        }                                                                   \
        float dv = __half2float(hv[(T) & 31]);                              \
        float m = fminf(s2, fminf(s1, cur));                                \
        float e = fexp2(m - s2) + fexp2(m - s1) + fexp2(m - cur);           \
        float val = dv + m - flog2(e);                                      \
        s2 = s1;                                                            \
        if (extRound && tstar == (T) && lane == it) extv = val;             \
        int jl = (T) - lane;                                                \
        if ((unsigned)jl < 32u) {                                           \
          cur = val;                                                        \
          if ((T) >= 63) { if (wr63) bndW[jl + 1] = val; }                  \
        }                                                                   \
      } while (0)

#pragma unroll
        for (int T = 0; T < 96; ++T) STEP(T);
#undef STEP
        if (extRound && lane == it) dist[p_id] = extv * scale;
        leftR = cur;
      }
    }
  }
}

// ---------------------------------------------------------------------------
// Loss reduction over 16 windows (validated rounds 1-10).
// ---------------------------------------------------------------------------
__device__ __forceinline__ float median5(const float* v) {
#pragma unroll
  for (int i = 0; i < 5; ++i) {
    int c = 0;
#pragma unroll
    for (int j = 0; j < 5; ++j)
      c += (v[j] < v[i]) || ((v[j] == v[i]) && (j < i));
    if (c == 2) return v[i];
  }
  return v[0];
}

__global__ void loss_kernel(const float* __restrict__ dist, float* __restrict__ out) {
  __shared__ float acc[NWIN];
  const int w = threadIdx.x;
  if (w < NWIN) {
    float dg[5], dn[10];
#pragma unroll
    for (int g = 0; g < 5; ++g)  dg[g] = dist[w * PERW + g];
#pragma unroll
    for (int n = 0; n < 10; ++n) dn[n] = dist[w * PERW + 5 + n];

    float lk = 0.f; int nz = 0;
#pragma unroll
    for (int g = 0; g < 5; ++g)
#pragma unroll
      for (int n = 0; n < 10; ++n) {
        float t = dg[g] + 1.0f - dn[n];
        if (t > 0.f) { lk += t; ++nz; }
      }
    float lv = lk / (1.0f + (float)nz);

    float sp = 0.f;
#pragma unroll
    for (int g = 0; g < 5; ++g) sp += dg[g];
    float only_pos = sp * (0.01f / 5.0f);

    float mg = median5(dg);
    float ms = median5(dn);

    int err = 0;
#pragma unroll
    for (int g = 0; g < 5; ++g) {
      err += ((dg[g] < mg) && (dn[g] < mg));
      err += ((dg[g] > ms) && (dn[g] > ms));
      err += ((dg[g] < mg) && (dn[5 + g] < mg));
      err += ((dg[g] > ms) && (dn[5 + g] > ms));
    }
    float offset = (float)err * (1.0f / 50.0f);

    acc[w] = lv + only_pos + offset;
  }
  __syncthreads();
  if (w == 0) {
    float s = 0.f;
#pragma unroll
    for (int i = 0; i < NWIN; ++i) s += acc[i];
    out[0] = s / (float)NWIN;
  }
}

// ---------------------------------------------------------------------------
extern "C" void kernel_launch(void* const* d_in, const int* in_sizes, int n_in,
                              void* d_out, int out_size, void* d_ws, size_t ws_size,
                              hipStream_t stream) {
  const float* data = (const float*)d_in[0];
  const int* lens   = (const int*)d_in[1];
  float* dist = (float*)d_ws;

  sdtw_kernel<<<NPAIR, 768, 0, stream>>>(data, lens, dist);
  loss_kernel<<<1, 64, 0, stream>>>(dist, (float*)d_out);
}